// Round 1
// baseline (134.286 us; speedup 1.0000x reference)
//
#include <hip/hip_runtime.h>
#include <hip/hip_bf16.h>
#include <math.h>

#define BB 4
#define HH 8
#define PP 32
#define NN 32
#define DD 16
#define LL 1024      // PP*NN
#define WINW 10
#define NFF 6
#define PREDL 96
#define SEQL 512
#define EPSF 1.1920928955078125e-07f
#define KROW 24      // shorts per staged key row (48 B, 16B-aligned)
#define KTS 296      // shorts per VT row (288 keys + 8 pad; 592 B, 16B-aligned)
#define PROW 40      // shorts per P row (80 B, 16B-aligned)
#define XROW 20      // floats per xls row (80 B, 16B-aligned)

typedef __attribute__((ext_vector_type(8))) short bf16x8;
typedef __attribute__((ext_vector_type(4))) float f32x4;

__device__ inline short f2bs(float f) {
    __hip_bfloat16 h = __float2bfloat16(f);
    return *reinterpret_cast<short*>(&h);
}

// ======= MFMA fused layer: signed banded attention + RMSNorm + convFFN + RMSNorm ===
// Grid: 1024 blocks x 256 (4 waves per (b,h,patch)).
//   wave = (qh, ch): qh = query half (16 queries), ch = chunk half.
//   ch==0 handles key chunks [0,4), ch==1 handles [4,nstage) -> per-wave serial
//   chain halves vs the 2-wave version, and occupancy doubles (4 waves/SIMD).
// Partial (Op,On,lp,ln) of ch==1 waves are merged into ch==0 waves through a
// small dedicated LDS buffer (one extra barrier). Epilogue (attn-norm + convFFN
// + ffn-norm) runs on the two ch==0 waves with ALL 64 lanes (lane = 16 queries
// x 4 i-groups; causal conv is data-parallel over i).
__global__ __launch_bounds__(256) void layer_kernel(
    const float* __restrict__ hin, float* __restrict__ hout,
    const float* __restrict__ log_scales, const float* __restrict__ attn_norm,
    const float* __restrict__ up_w, const float* __restrict__ down_w,
    const float* __restrict__ ffn_norm, int layer)
{
    __shared__ short hK[9 * 32 * KROW];   // 13.8 KB keys row-major
    __shared__ short VT[16 * KTS];        //  9.5 KB keys dim-major (transposed)
    __shared__ short Pp[4][16 * PROW];    //  5.0 KB (per-wave)
    __shared__ short Pn[4][16 * PROW];    //  5.0 KB
    __shared__ float xls[32 * XROW];      //  2.5 KB
    __shared__ float comb[2][64][8];      //  4.0 KB partial Op/On exchange
    __shared__ float combl[2][2][16];     //  256 B partial lp/ln exchange

    int blk = blockIdx.x;
    int bh  = blk >> 5;            // (b*8+h)
    int hh  = bh & 7;
    int p0  = blk & 31;
    int nstage = min(9, (PP - 1) - p0);

    int tid  = threadIdx.x;
    int wid  = tid >> 6;           // wave id
    int qh   = wid >> 1;           // query half (0/1)
    int ch   = wid & 1;            // chunk half (0/1)
    int lane = tid & 63;
    int quad = lane >> 4, n16 = lane & 15;

    // ---- stage keys: fp32 -> bf16, row-major + transposed (256 threads) ----
    {
        const float4* src = (const float4*)(hin + ((size_t)bh * LL + (p0 + 1) * NN) * DD);
        int nf4 = nstage * 128;
        #pragma unroll
        for (int k = 0; k < 5; ++k) {
            int i = tid + k * 256;
            if (i < nf4) {
                int row = i >> 2, j = i & 3;
                float4 v = src[i];
                short s0 = f2bs(v.x), s1 = f2bs(v.y), s2 = f2bs(v.z), s3 = f2bs(v.w);
                unsigned long long u =
                      (unsigned long long)(unsigned short)s0
                    | ((unsigned long long)(unsigned short)s1 << 16)
                    | ((unsigned long long)(unsigned short)s2 << 32)
                    | ((unsigned long long)(unsigned short)s3 << 48);
                *(unsigned long long*)&hK[row * KROW + j * 4] = u;
                int d0 = j * 4;
                VT[(d0 + 0) * KTS + row] = s0;
                VT[(d0 + 1) * KTS + row] = s1;
                VT[(d0 + 2) * KTS + row] = s2;
                VT[(d0 + 3) * KTS + row] = s3;
            }
        }
    }

    // ---- preload Q A-frag and residual (global; overlaps staging) ----
    bf16x8 Aq;
    #pragma unroll
    for (int j = 0; j < 8; ++j) Aq[j] = 0;
    if (quad < 2) {
        const float* qp = hin + ((size_t)bh * LL + p0 * NN + qh * 16 + n16) * DD + quad * 8;
        #pragma unroll
        for (int j = 0; j < 8; ++j) Aq[j] = f2bs(qp[j]);
    }
    float rs[4] = {0.f, 0.f, 0.f, 0.f};
    if (ch == 0) {
        #pragma unroll
        for (int r = 0; r < 4; ++r)
            rs[r] = hin[((size_t)bh * LL + p0 * NN + qh * 16 + quad * 4 + r) * DD + n16];
    }

    float sc  = fminf(fmaxf(__expf(log_scales[layer]), 1.0f), 30.0f) * 0.25f;
    float sc2 = sc * 1.4426950408889634f;   // fold log2(e): exp(x) == exp2(sc2*s)

    __syncthreads();   // staging done

    // ---- chunk loop: ch==0 -> chunks [0,4), ch==1 -> chunks [4,nstage) ----
    f32x4 Op, On;
    Op[0] = Op[1] = Op[2] = Op[3] = 0.f;
    On[0] = On[1] = On[2] = On[3] = 0.f;
    float lpp[4] = {0.f, 0.f, 0.f, 0.f}, lnn[4] = {0.f, 0.f, 0.f, 0.f};
    short* myPp = Pp[wid];
    short* myPn = Pn[wid];

    int c0 = ch ? 4 : 0;
    int c1 = ch ? nstage : min(4, nstage);

    for (int c = c0; c < c1; ++c) {
        int kb = c * 32;
        #pragma unroll
        for (int kt = 0; kt < 2; ++kt) {
            bf16x8 Bk;
            #pragma unroll
            for (int j = 0; j < 8; ++j) Bk[j] = 0;
            if (quad < 2)
                Bk = *(const bf16x8*)&hK[(kb + kt * 16 + n16) * KROW + quad * 8];
            f32x4 z; z[0] = z[1] = z[2] = z[3] = 0.f;
            f32x4 S = __builtin_amdgcn_mfma_f32_16x16x32_bf16(Aq, Bk, z, 0, 0, 0);
            #pragma unroll
            for (int r = 0; r < 4; ++r) {
                float t  = sc2 * S[r];
                float ep = exp2f(t);
                float en = exp2f(-t);
                lpp[r] += ep; lnn[r] += en;
                int pr = quad * 4 + r, pc = kt * 16 + n16;
                myPp[pr * PROW + pc] = f2bs(ep);
                myPn[pr * PROW + pc] = f2bs(en);
            }
        }
        // PV: contiguous b128 frags (same-wave LDS ordering via lgkmcnt)
        bf16x8 Bv = *(const bf16x8*)&VT[n16 * KTS + kb + quad * 8];
        bf16x8 Ap = *(const bf16x8*)&myPp[n16 * PROW + quad * 8];
        bf16x8 An = *(const bf16x8*)&myPn[n16 * PROW + quad * 8];
        Op = __builtin_amdgcn_mfma_f32_16x16x32_bf16(Ap, Bv, Op, 0, 0, 0);
        On = __builtin_amdgcn_mfma_f32_16x16x32_bf16(An, Bv, On, 0, 0, 0);
    }

    // ---- reduce lp/ln over the 16 key-columns (both halves) ----
    #pragma unroll
    for (int r = 0; r < 4; ++r) {
        float a = lpp[r], b = lnn[r];
        a += __shfl_xor(a, 1); a += __shfl_xor(a, 2); a += __shfl_xor(a, 4); a += __shfl_xor(a, 8);
        b += __shfl_xor(b, 1); b += __shfl_xor(b, 2); b += __shfl_xor(b, 4); b += __shfl_xor(b, 8);
        lpp[r] = a; lnn[r] = b;
    }

    // ---- merge ch==1 partials into ch==0 waves ----
    if (ch == 1) {
        *(f32x4*)&comb[qh][lane][0] = Op;
        *(f32x4*)&comb[qh][lane][4] = On;
        if (n16 == 0) {
            #pragma unroll
            for (int r = 0; r < 4; ++r) {
                combl[qh][0][quad * 4 + r] = lpp[r];
                combl[qh][1][quad * 4 + r] = lnn[r];
            }
        }
    }
    __syncthreads();
    if (ch == 1) return;   // no barriers past this point

    {
        f32x4 o2 = *(const f32x4*)&comb[qh][lane][0];
        f32x4 n2 = *(const f32x4*)&comb[qh][lane][4];
        #pragma unroll
        for (int r = 0; r < 4; ++r) {
            Op[r] += o2[r];
            On[r] += n2[r];
            lpp[r] += combl[qh][0][quad * 4 + r];
            lnn[r] += combl[qh][1][quad * 4 + r];
        }
    }

    // ---- residual + attn RMSNorm (C-layout), stash rows to xls ----
    #pragma unroll
    for (int r = 0; r < 4; ++r) {
        float lp = lpp[r], ln = lnn[r];
        float rl = (lp > 0.f) ? (1.0f / lp) : 0.f;
        float rn = (ln > 0.f) ? (1.0f / ln) : 0.f;
        float v  = rs[r] + Op[r] * rl - On[r] * rn;
        float ss = v * v;
        ss += __shfl_xor(ss, 1); ss += __shfl_xor(ss, 2);
        ss += __shfl_xor(ss, 4); ss += __shfl_xor(ss, 8);
        float rr = rsqrtf(ss * (1.0f / 16.0f) + EPSF);
        xls[(qh * 16 + quad * 4 + r) * XROW + n16] = v * rr * attn_norm[layer * DD + n16];
    }
    // this wave wrote all 16 of its xls rows -> same-wave LDS ordering, no barrier

    // ---- conv-FFN + residual + RMSNorm: all 64 lanes (16 q x 4 i-groups) ----
    {
        int q = qh * 16 + n16;       // row in xls / output row within block
        int g = quad;                // i-group: i = 4g..4g+3

        const float* uw = up_w + (size_t)(layer * 2 * HH + 2 * hh) * 3;
        float w00 = uw[0], w01 = uw[1], w02 = uw[2];
        float w10 = uw[3], w11 = uw[4], w12 = uw[5];
        const float* dw = down_w + (size_t)(layer * HH + hh) * 2;
        float dc0 = dw[0], dc1 = dw[1];

        float xm2 = g ? xls[q * XROW + 4 * g - 2] : 0.f;
        float xm1 = g ? xls[q * XROW + 4 * g - 1] : 0.f;
        float4 xv = *(const float4*)&xls[q * XROW + 4 * g];
        float xa[6] = {xm2, xm1, xv.x, xv.y, xv.z, xv.w};

        float v4[4], ss = 0.f;
        #pragma unroll
        for (int i = 0; i < 4; ++i) {
            float u0 = w00 * xa[i] + w01 * xa[i + 1] + w02 * xa[i + 2];
            float u1 = w10 * xa[i] + w11 * xa[i + 1] + w12 * xa[i + 2];
            float g0 = 0.5f * u0 * (1.0f + erff(u0 * 0.7071067811865475f));
            float g1 = 0.5f * u1 * (1.0f + erff(u1 * 0.7071067811865475f));
            float vv = xa[i + 2] + dc0 * g0 + dc1 * g1;
            v4[i] = vv; ss += vv * vv;
        }
        ss += __shfl_xor(ss, 16); ss += __shfl_xor(ss, 32);
        float r2 = rsqrtf(ss * (1.0f / 16.0f) + EPSF);

        const float4 fn = *(const float4*)&ffn_norm[layer * DD + 4 * g];
        float* op = hout + ((size_t)bh * LL + p0 * NN + q) * DD + 4 * g;
        float4 o;
        o.x = v4[0] * r2 * fn.x;
        o.y = v4[1] * r2 * fn.y;
        o.z = v4[2] * r2 * fn.z;
        o.w = v4[3] * r2 * fn.w;
        *(float4*)op = o;
    }
}

// ---------------- tail: head-mix + forecast projection, and x passthrough ----
__global__ void tail_kernel(const float* __restrict__ h, const float* __restrict__ mw_,
                            const float* __restrict__ mb_, const float* __restrict__ fw_,
                            const float* __restrict__ fb_, const float* __restrict__ x,
                            float* __restrict__ out)
{
    int t = blockIdx.x * 256 + threadIdx.x;
    if (t < BB * DD * NFF * NN) {
        int n = t & 31;
        int r = t >> 5;
        int fi = r % NFF; r /= NFF;
        int d = r & 15;
        int b = r >> 4;

        float mw[8];
        #pragma unroll
        for (int k = 0; k < 8; ++k) mw[k] = mw_[k];
        float mb = mb_[0];

        float acc = fb_[fi];
        for (int p = 0; p < PP; ++p) {
            float m = mb;
            #pragma unroll
            for (int k = 0; k < 8; ++k)
                m += h[(size_t)(((b * HH + k) * LL) + p * NN + n) * DD + d] * mw[k];
            acc += m * fw_[fi * PP + p];
        }
        out[t] = acc;   // flat index == t: b*3072 + (d*6+fi)*32 + n
    } else {
        int u4 = t - BB * DD * NFF * NN;           // float4 index into x
        if (u4 < BB * SEQL * NN / 4) {
            const float4* x4 = (const float4*)x;
            float4* o4 = (float4*)(out + BB * PREDL * NN);
            o4[u4] = x4[u4];
        }
    }
}

// ---------------- host-side input identification by element count ----------------
static int find_by_size(const int* s, int n, int want, int occurrence) {
    int seen = 0;
    for (int i = 0; i < n; ++i)
        if (s[i] == want) { if (seen == occurrence) return i; ++seen; }
    return -1;
}

extern "C" void kernel_launch(void* const* d_in, const int* in_sizes, int n_in,
                              void* d_out, int out_size, void* d_ws, size_t ws_size,
                              hipStream_t stream) {
    int it  = find_by_size(in_sizes, n_in, 524288, 0);
    int ix  = find_by_size(in_sizes, n_in, 65536, 0);
    int ils = find_by_size(in_sizes, n_in, 2, 0);
    int ian = find_by_size(in_sizes, n_in, 32, 0);   // attn_norm_w (1st 32)
    int icu = find_by_size(in_sizes, n_in, 96, 0);
    int icd = find_by_size(in_sizes, n_in, 32, 1);   // conv_down_w (2nd 32)
    int ifn = find_by_size(in_sizes, n_in, 32, 2);   // ffn_norm_w  (3rd 32)
    int imw = find_by_size(in_sizes, n_in, 8, 0);
    int imb = find_by_size(in_sizes, n_in, 1, 0);
    int ifw = find_by_size(in_sizes, n_in, 192, 0);
    int ifb = find_by_size(in_sizes, n_in, 6, 0);
    if (it < 0 || ix < 0 || ils < 0 || ian < 0 || icu < 0 || icd < 0 ||
        ifn < 0 || imw < 0 || imb < 0 || ifw < 0 || ifb < 0) {
        it = 0; ix = 1; ils = 2; ian = 3; icu = 4; icd = 5; ifn = 6;
        imw = 7; imb = 8; ifw = 9; ifb = 10;
    }

    const float* tokens     = (const float*)d_in[it];
    const float* x_orig     = (const float*)d_in[ix];
    const float* log_scales = (const float*)d_in[ils];
    const float* attn_norm  = (const float*)d_in[ian];
    const float* up_w       = (const float*)d_in[icu];
    const float* down_w     = (const float*)d_in[icd];
    const float* ffn_norm   = (const float*)d_in[ifn];
    const float* mix_w      = (const float*)d_in[imw];
    const float* mix_b      = (const float*)d_in[imb];
    const float* fore_w     = (const float*)d_in[ifw];
    const float* fore_b     = (const float*)d_in[ifb];
    float* out = (float*)d_out;          // fp32 output (verified round 7)

    const size_t NH = (size_t)BB * HH * LL * DD;
    float* hA = (float*)d_ws;        // 2 MB
    float* hB = hA + NH;             // 2 MB

    layer_kernel<<<1024, 256, 0, stream>>>(tokens, hA, log_scales, attn_norm,
                                           up_w, down_w, ffn_norm, 0);
    layer_kernel<<<1024, 256, 0, stream>>>(hA, hB, log_scales, attn_norm,
                                           up_w, down_w, ffn_norm, 1);
    const int tail_threads = BB * DD * NFF * NN + BB * SEQL * NN / 4;  // 12288 + 16384
    tail_kernel<<<(tail_threads + 255) / 256, 256, 0, stream>>>(
        hB, mix_w, mix_b, fore_w, fore_b, x_orig, out);
}

// Round 3
// 118.615 us; speedup vs baseline: 1.1321x; 1.1321x over previous
//
#include <hip/hip_runtime.h>
#include <hip/hip_bf16.h>
#include <math.h>

#define BB 4
#define HH 8
#define PP 32
#define NN 32
#define DD 16
#define LL 1024      // PP*NN
#define WINW 10
#define NFF 6
#define PREDL 96
#define SEQL 512
#define EPSF 1.1920928955078125e-07f
#define KROW 24      // shorts per staged key row (48 B, 16B-aligned)
#define KTS 296      // shorts per VT row (288 keys + 8 pad; 592 B, 16B-aligned)
#define PROW 40      // shorts per P row (80 B, 16B-aligned)
#define XROW 20      // floats per xls row (80 B, 16B-aligned)

typedef __attribute__((ext_vector_type(8))) short bf16x8;
typedef __attribute__((ext_vector_type(4))) float f32x4;

__device__ inline short f2bs(float f) {
    __hip_bfloat16 h = __float2bfloat16(f);
    return *reinterpret_cast<short*>(&h);
}

// ======= MFMA fused layer: signed banded attention + RMSNorm + convFFN + RMSNorm ===
// Grid: 1024 blocks x 256 (4 waves per (b,h,patch)).
//   wave = (qh, ch): qh = query half (16 queries), ch = chunk half.
// ch==1 partials merged into ch==0 waves via comb/combl LDS (one barrier).
// Epilogue on ch==0 waves with all 64 lanes (16 q x 4 i-groups).
// Layer 0 additionally streams the x-passthrough copy (16 float4 per block).
__global__ __launch_bounds__(256) void layer_kernel(
    const float* __restrict__ hin, float* __restrict__ hout,
    const float* __restrict__ log_scales, const float* __restrict__ attn_norm,
    const float* __restrict__ up_w, const float* __restrict__ down_w,
    const float* __restrict__ ffn_norm, int layer,
    const float* __restrict__ xsrc, float* __restrict__ xdst)
{
    __shared__ short hK[9 * 32 * KROW];   // 13.8 KB keys row-major
    __shared__ short VT[16 * KTS];        //  9.5 KB keys dim-major (transposed)
    __shared__ short Pp[4][16 * PROW];    //  5.0 KB (per-wave)
    __shared__ short Pn[4][16 * PROW];    //  5.0 KB
    __shared__ float xls[32 * XROW];      //  2.5 KB
    __shared__ float comb[2][64][8];      //  4.0 KB partial Op/On exchange
    __shared__ float combl[2][2][16];     //  256 B partial lp/ln exchange

    int blk = blockIdx.x;
    int bh  = blk >> 5;            // (b*8+h)
    int hh  = bh & 7;
    int p0  = blk & 31;
    int nstage = min(9, (PP - 1) - p0);

    int tid  = threadIdx.x;
    int wid  = tid >> 6;           // wave id
    int qh   = wid >> 1;           // query half (0/1)
    int ch   = wid & 1;            // chunk half (0/1)
    int lane = tid & 63;
    int quad = lane >> 4, n16 = lane & 15;

    // ---- x passthrough (layer 0 only): 16 float4 per block ----
    if (xsrc && tid < 16) {
        const float4* x4 = (const float4*)xsrc;
        float4* o4 = (float4*)xdst;
        o4[blk * 16 + tid] = x4[blk * 16 + tid];
    }

    // ---- stage keys: fp32 -> bf16, row-major + transposed (256 threads) ----
    {
        const float4* src = (const float4*)(hin + ((size_t)bh * LL + (p0 + 1) * NN) * DD);
        int nf4 = nstage * 128;
        #pragma unroll
        for (int k = 0; k < 5; ++k) {
            int i = tid + k * 256;
            if (i < nf4) {
                int row = i >> 2, j = i & 3;
                float4 v = src[i];
                short s0 = f2bs(v.x), s1 = f2bs(v.y), s2 = f2bs(v.z), s3 = f2bs(v.w);
                unsigned long long u =
                      (unsigned long long)(unsigned short)s0
                    | ((unsigned long long)(unsigned short)s1 << 16)
                    | ((unsigned long long)(unsigned short)s2 << 32)
                    | ((unsigned long long)(unsigned short)s3 << 48);
                *(unsigned long long*)&hK[row * KROW + j * 4] = u;
                int d0 = j * 4;
                VT[(d0 + 0) * KTS + row] = s0;
                VT[(d0 + 1) * KTS + row] = s1;
                VT[(d0 + 2) * KTS + row] = s2;
                VT[(d0 + 3) * KTS + row] = s3;
            }
        }
    }

    // ---- preload Q A-frag and residual (global; overlaps staging) ----
    bf16x8 Aq;
    #pragma unroll
    for (int j = 0; j < 8; ++j) Aq[j] = 0;
    if (quad < 2) {
        const float* qp = hin + ((size_t)bh * LL + p0 * NN + qh * 16 + n16) * DD + quad * 8;
        #pragma unroll
        for (int j = 0; j < 8; ++j) Aq[j] = f2bs(qp[j]);
    }
    float rs[4] = {0.f, 0.f, 0.f, 0.f};
    if (ch == 0) {
        #pragma unroll
        for (int r = 0; r < 4; ++r)
            rs[r] = hin[((size_t)bh * LL + p0 * NN + qh * 16 + quad * 4 + r) * DD + n16];
    }

    float sc  = fminf(fmaxf(__expf(log_scales[layer]), 1.0f), 30.0f) * 0.25f;
    float sc2 = sc * 1.4426950408889634f;   // fold log2(e): exp(x) == exp2(sc2*s)

    __syncthreads();   // staging done

    // ---- chunk loop: ch==0 -> chunks [0,4), ch==1 -> chunks [4,nstage) ----
    f32x4 Op, On;
    Op[0] = Op[1] = Op[2] = Op[3] = 0.f;
    On[0] = On[1] = On[2] = On[3] = 0.f;
    float lpp[4] = {0.f, 0.f, 0.f, 0.f}, lnn[4] = {0.f, 0.f, 0.f, 0.f};
    short* myPp = Pp[wid];
    short* myPn = Pn[wid];

    int c0 = ch ? 4 : 0;
    int c1 = ch ? nstage : min(4, nstage);

    for (int c = c0; c < c1; ++c) {
        int kb = c * 32;
        #pragma unroll
        for (int kt = 0; kt < 2; ++kt) {
            bf16x8 Bk;
            #pragma unroll
            for (int j = 0; j < 8; ++j) Bk[j] = 0;
            if (quad < 2)
                Bk = *(const bf16x8*)&hK[(kb + kt * 16 + n16) * KROW + quad * 8];
            f32x4 z; z[0] = z[1] = z[2] = z[3] = 0.f;
            f32x4 S = __builtin_amdgcn_mfma_f32_16x16x32_bf16(Aq, Bk, z, 0, 0, 0);
            #pragma unroll
            for (int r = 0; r < 4; ++r) {
                float t  = sc2 * S[r];
                float ep = exp2f(t);
                float en = exp2f(-t);
                lpp[r] += ep; lnn[r] += en;
                int pr = quad * 4 + r, pc = kt * 16 + n16;
                myPp[pr * PROW + pc] = f2bs(ep);
                myPn[pr * PROW + pc] = f2bs(en);
            }
        }
        // PV: contiguous b128 frags (same-wave LDS ordering via lgkmcnt)
        bf16x8 Bv = *(const bf16x8*)&VT[n16 * KTS + kb + quad * 8];
        bf16x8 Ap = *(const bf16x8*)&myPp[n16 * PROW + quad * 8];
        bf16x8 An = *(const bf16x8*)&myPn[n16 * PROW + quad * 8];
        Op = __builtin_amdgcn_mfma_f32_16x16x32_bf16(Ap, Bv, Op, 0, 0, 0);
        On = __builtin_amdgcn_mfma_f32_16x16x32_bf16(An, Bv, On, 0, 0, 0);
    }

    // ---- reduce lp/ln over the 16 key-columns (both halves) ----
    #pragma unroll
    for (int r = 0; r < 4; ++r) {
        float a = lpp[r], b = lnn[r];
        a += __shfl_xor(a, 1); a += __shfl_xor(a, 2); a += __shfl_xor(a, 4); a += __shfl_xor(a, 8);
        b += __shfl_xor(b, 1); b += __shfl_xor(b, 2); b += __shfl_xor(b, 4); b += __shfl_xor(b, 8);
        lpp[r] = a; lnn[r] = b;
    }

    // ---- merge ch==1 partials into ch==0 waves ----
    if (ch == 1) {
        *(f32x4*)&comb[qh][lane][0] = Op;
        *(f32x4*)&comb[qh][lane][4] = On;
        if (n16 == 0) {
            #pragma unroll
            for (int r = 0; r < 4; ++r) {
                combl[qh][0][quad * 4 + r] = lpp[r];
                combl[qh][1][quad * 4 + r] = lnn[r];
            }
        }
    }
    __syncthreads();
    if (ch == 1) return;   // no barriers past this point

    {
        f32x4 o2 = *(const f32x4*)&comb[qh][lane][0];
        f32x4 n2 = *(const f32x4*)&comb[qh][lane][4];
        #pragma unroll
        for (int r = 0; r < 4; ++r) {
            Op[r] += o2[r];
            On[r] += n2[r];
            lpp[r] += combl[qh][0][quad * 4 + r];
            lnn[r] += combl[qh][1][quad * 4 + r];
        }
    }

    // ---- residual + attn RMSNorm (C-layout), stash rows to xls ----
    #pragma unroll
    for (int r = 0; r < 4; ++r) {
        float lp = lpp[r], ln = lnn[r];
        float rl = (lp > 0.f) ? (1.0f / lp) : 0.f;
        float rn = (ln > 0.f) ? (1.0f / ln) : 0.f;
        float v  = rs[r] + Op[r] * rl - On[r] * rn;
        float ss = v * v;
        ss += __shfl_xor(ss, 1); ss += __shfl_xor(ss, 2);
        ss += __shfl_xor(ss, 4); ss += __shfl_xor(ss, 8);
        float rr = rsqrtf(ss * (1.0f / 16.0f) + EPSF);
        xls[(qh * 16 + quad * 4 + r) * XROW + n16] = v * rr * attn_norm[layer * DD + n16];
    }
    // this wave wrote all 16 of its xls rows -> same-wave LDS ordering, no barrier

    // ---- conv-FFN + residual + RMSNorm: all 64 lanes (16 q x 4 i-groups) ----
    {
        int q = qh * 16 + n16;       // row in xls / output row within block
        int g = quad;                // i-group: i = 4g..4g+3

        const float* uw = up_w + (size_t)(layer * 2 * HH + 2 * hh) * 3;
        float w00 = uw[0], w01 = uw[1], w02 = uw[2];
        float w10 = uw[3], w11 = uw[4], w12 = uw[5];
        const float* dw = down_w + (size_t)(layer * HH + hh) * 2;
        float dc0 = dw[0], dc1 = dw[1];

        float xm2 = g ? xls[q * XROW + 4 * g - 2] : 0.f;
        float xm1 = g ? xls[q * XROW + 4 * g - 1] : 0.f;
        float4 xv = *(const float4*)&xls[q * XROW + 4 * g];
        float xa[6] = {xm2, xm1, xv.x, xv.y, xv.z, xv.w};

        float v4[4], ss = 0.f;
        #pragma unroll
        for (int i = 0; i < 4; ++i) {
            float u0 = w00 * xa[i] + w01 * xa[i + 1] + w02 * xa[i + 2];
            float u1 = w10 * xa[i] + w11 * xa[i + 1] + w12 * xa[i + 2];
            float g0 = 0.5f * u0 * (1.0f + erff(u0 * 0.7071067811865475f));
            float g1 = 0.5f * u1 * (1.0f + erff(u1 * 0.7071067811865475f));
            float vv = xa[i + 2] + dc0 * g0 + dc1 * g1;
            v4[i] = vv; ss += vv * vv;
        }
        ss += __shfl_xor(ss, 16); ss += __shfl_xor(ss, 32);
        float r2 = rsqrtf(ss * (1.0f / 16.0f) + EPSF);

        const float4 fn = *(const float4*)&ffn_norm[layer * DD + 4 * g];
        float* op = hout + ((size_t)bh * LL + p0 * NN + q) * DD + 4 * g;
        float4 o;
        o.x = v4[0] * r2 * fn.x;
        o.y = v4[1] * r2 * fn.y;
        o.z = v4[2] * r2 * fn.z;
        o.w = v4[3] * r2 * fn.w;
        *(float4*)op = o;
    }
}

// ---------------- tail: head-mix + forecast projection (coalesced, 4 blocks) ----
// Block b handles batch b. Thread mapping: tid = 8*n + j, d0 = 2*j.
// A wave's 64 lanes cover 8 n x 16 d = 512 contiguous floats (2 KB) per (k,p)
// -> hB is read exactly once, fully coalesced.
__global__ __launch_bounds__(256) void tail_kernel(
    const float* __restrict__ h, const float* __restrict__ mw_,
    const float* __restrict__ mb_, const float* __restrict__ fw_,
    const float* __restrict__ fb_, float* __restrict__ out)
{
    int b   = blockIdx.x;
    int tid = threadIdx.x;
    int n   = tid >> 3;           // 0..31
    int d0  = (2 * tid) & 15;     // even d; thread owns (n, d0) and (n, d0+1)

    float mw[8];
    #pragma unroll
    for (int k = 0; k < 8; ++k) mw[k] = mw_[k];
    float mb = mb_[0];

    float acc0[NFF] = {0.f, 0.f, 0.f, 0.f, 0.f, 0.f};
    float acc1[NFF] = {0.f, 0.f, 0.f, 0.f, 0.f, 0.f};

    for (int p = 0; p < PP; ++p) {
        float m0 = mb, m1 = mb;
        #pragma unroll
        for (int k = 0; k < 8; ++k) {
            const float* hp = h + (size_t)(((b * HH + k) * LL) + p * NN + n) * DD + d0;
            float2 hv = *(const float2*)hp;
            m0 += hv.x * mw[k];
            m1 += hv.y * mw[k];
        }
        #pragma unroll
        for (int fi = 0; fi < NFF; ++fi) {
            float w = fw_[fi * PP + p];
            acc0[fi] += m0 * w;
            acc1[fi] += m1 * w;
        }
    }
    #pragma unroll
    for (int fi = 0; fi < NFF; ++fi) {
        float fb = fb_[fi];
        out[((b * DD + d0) * NFF + fi) * NN + n]     = acc0[fi] + fb;
        out[((b * DD + d0 + 1) * NFF + fi) * NN + n] = acc1[fi] + fb;
    }
}

// ---------------- host-side input identification by element count ----------------
static int find_by_size(const int* s, int n, int want, int occurrence) {
    int seen = 0;
    for (int i = 0; i < n; ++i)
        if (s[i] == want) { if (seen == occurrence) return i; ++seen; }
    return -1;
}

extern "C" void kernel_launch(void* const* d_in, const int* in_sizes, int n_in,
                              void* d_out, int out_size, void* d_ws, size_t ws_size,
                              hipStream_t stream) {
    int it  = find_by_size(in_sizes, n_in, 524288, 0);
    int ix  = find_by_size(in_sizes, n_in, 65536, 0);
    int ils = find_by_size(in_sizes, n_in, 2, 0);
    int ian = find_by_size(in_sizes, n_in, 32, 0);   // attn_norm_w (1st 32)
    int icu = find_by_size(in_sizes, n_in, 96, 0);
    int icd = find_by_size(in_sizes, n_in, 32, 1);   // conv_down_w (2nd 32)
    int ifn = find_by_size(in_sizes, n_in, 32, 2);   // ffn_norm_w  (3rd 32)
    int imw = find_by_size(in_sizes, n_in, 8, 0);
    int imb = find_by_size(in_sizes, n_in, 1, 0);
    int ifw = find_by_size(in_sizes, n_in, 192, 0);
    int ifb = find_by_size(in_sizes, n_in, 6, 0);
    if (it < 0 || ix < 0 || ils < 0 || ian < 0 || icu < 0 || icd < 0 ||
        ifn < 0 || imw < 0 || imb < 0 || ifw < 0 || ifb < 0) {
        it = 0; ix = 1; ils = 2; ian = 3; icu = 4; icd = 5; ifn = 6;
        imw = 7; imb = 8; ifw = 9; ifb = 10;
    }

    const float* tokens     = (const float*)d_in[it];
    const float* x_orig     = (const float*)d_in[ix];
    const float* log_scales = (const float*)d_in[ils];
    const float* attn_norm  = (const float*)d_in[ian];
    const float* up_w       = (const float*)d_in[icu];
    const float* down_w     = (const float*)d_in[icd];
    const float* ffn_norm   = (const float*)d_in[ifn];
    const float* mix_w      = (const float*)d_in[imw];
    const float* mix_b      = (const float*)d_in[imb];
    const float* fore_w     = (const float*)d_in[ifw];
    const float* fore_b     = (const float*)d_in[ifb];
    float* out = (float*)d_out;

    const size_t NH = (size_t)BB * HH * LL * DD;
    float* hA = (float*)d_ws;        // 2 MB
    float* hB = hA + NH;             // 2 MB

    layer_kernel<<<1024, 256, 0, stream>>>(tokens, hA, log_scales, attn_norm,
                                           up_w, down_w, ffn_norm, 0,
                                           x_orig, out + BB * PREDL * NN);
    layer_kernel<<<1024, 256, 0, stream>>>(hA, hB, log_scales, attn_norm,
                                           up_w, down_w, ffn_norm, 1,
                                           (const float*)nullptr, (float*)nullptr);
    tail_kernel<<<BB, 256, 0, stream>>>(hB, mix_w, mix_b, fore_w, fore_b, out);
}